// Round 8
// baseline (223.256 us; speedup 1.0000x reference)
//
#include <hip/hip_runtime.h>

#define B_ROWS 16384
#define D_IN   1024
#define H_DIM  256
#define N_EXP  8
#define N_TASK 4
#define NKT    16   // K-tiles of 64 in D_IN

typedef short bf16x8 __attribute__((ext_vector_type(8)));
typedef float f32x4  __attribute__((ext_vector_type(4)));
typedef unsigned short u16x8 __attribute__((ext_vector_type(8)));

static __device__ __forceinline__ unsigned short f2bf(float f) {
  unsigned int u = __float_as_uint(f);
  u += 0x7fffu + ((u >> 16) & 1u);   // RNE
  return (unsigned short)(u >> 16);
}
static __device__ __forceinline__ float bf2f(unsigned short u) {
  return __uint_as_float(((unsigned int)u) << 16);
}

// workspace layout (bytes)
#define WS_XB   0u          // ushort[16384*1024]  = 33,554,432 B
#define WS_WET  33554432u   // ushort[8*256*1024]  =  4,194,304 B
#define WS_GT   37814272u   // float [32*16384]    =  2,097,152 B (transposed probs Gt[t*8+e][row])

// ---------------------------------------------------------------------------
// Kernel 1: merged prep + gates, 512 threads/block.
// blocks [0,256): We cast+transpose, TWO 64x64 tiles per block.
// blocks [256,768): gates+cast for 32 rows each: stage Wg fp32->bf16 LDS
// [n][k], stream x (coalesced), cast->x_b, 32-col VALU dot per thread
// K-slice, shfl-butterfly K-reduce, in-register softmax -> Gt[t*8+e][row].
// ---------------------------------------------------------------------------
__global__ __launch_bounds__(512) void k_prep_gates(const float* __restrict__ x,
                                                    const float* __restrict__ We,
                                                    const float* __restrict__ Wg,
                                                    unsigned short* __restrict__ x_b,
                                                    unsigned short* __restrict__ We_t,
                                                    const float* __restrict__ bg,
                                                    float* __restrict__ Gt) {
  __shared__ char smem[66048];   // union: 2 We-tiles (2x9216B) | wgs [32][1032] u16
  int bid = blockIdx.x;
  int t = threadIdx.x;

  if (bid < 256) {
    // ---- two 64x64 tiles of We: [k][h] -> [h][k] ----
    unsigned short (*tile)[72] = (unsigned short (*)[72])(smem + (t >> 8) * 9216);
    int tl2 = bid * 2 + (t >> 8);    // 0..511
    int e = tl2 >> 6;
    int tl = tl2 & 63;
    int k0 = (tl >> 2) * 64, h0 = (tl & 3) * 64;
    int tt = t & 255;
    const float* src = We + (size_t)e * (D_IN * H_DIM);
#pragma unroll
    for (int i = 0; i < 4; ++i) {
      int kk = (tt >> 4) + i * 16;
      int hh = (tt & 15) * 4;
      float4 v = *(const float4*)(src + (size_t)(k0 + kk) * H_DIM + h0 + hh);
      tile[hh + 0][kk] = f2bf(v.x);
      tile[hh + 1][kk] = f2bf(v.y);
      tile[hh + 2][kk] = f2bf(v.z);
      tile[hh + 3][kk] = f2bf(v.w);
    }
    __syncthreads();
    unsigned short* dst = We_t + (size_t)e * (H_DIM * D_IN);
#pragma unroll
    for (int i = 0; i < 4; ++i) {
      int hh = (tt >> 4) + i * 16;
      int kk = (tt & 15) * 4;
      ushort4 u = *(const ushort4*)&tile[hh][kk];
      *(ushort4*)(dst + (size_t)(h0 + hh) * D_IN + k0 + kk) = u;
    }
    return;
  }

  // ---- gates + x-cast ----
  unsigned short* wgs = (unsigned short*)smem;   // [32][1032] bf16, row = gate-col n
  int m0 = (bid - 256) * 32;

  // stage Wg[4][1024][8] fp32 -> wgs[n = tsk*8+e][k] bf16 (~2-way banks)
#pragma unroll 4
  for (int i = 0; i < 16; ++i) {
    int idx = t * 4 + i * 2048;
    float4 v = *(const float4*)(Wg + idx);
    int kk = (idx >> 3) & 1023;
    int nb = (idx >> 13) * 8 + (idx & 7);
    wgs[(size_t)(nb + 0) * 1032 + kk] = f2bf(v.x);
    wgs[(size_t)(nb + 1) * 1032 + kk] = f2bf(v.y);
    wgs[(size_t)(nb + 2) * 1032 + kk] = f2bf(v.z);
    wgs[(size_t)(nb + 3) * 1032 + kk] = f2bf(v.w);
  }
  __syncthreads();

  int r = t >> 4, s = t & 15;     // row 0..31, K-slice 0..15
  const float* xrow = x + (size_t)(m0 + r) * D_IN;
  unsigned short* xbrow = x_b + (size_t)(m0 + r) * D_IN;

  float acc[32];
#pragma unroll
  for (int n = 0; n < 32; ++n) acc[n] = 0.f;

#pragma unroll 2
  for (int i = 0; i < 8; ++i) {
    int k0 = i * 128 + s * 8;
    float4 v0 = *(const float4*)(xrow + k0);
    float4 v1 = *(const float4*)(xrow + k0 + 4);
    float xf[8] = {v0.x, v0.y, v0.z, v0.w, v1.x, v1.y, v1.z, v1.w};
    bf16x8 a;
#pragma unroll
    for (int j = 0; j < 8; ++j) a[j] = (short)f2bf(xf[j]);
    *(bf16x8*)(xbrow + k0) = a;
#pragma unroll
    for (int n = 0; n < 32; ++n) {
      u16x8 wv = *(const u16x8*)&wgs[(size_t)n * 1032 + k0];
#pragma unroll
      for (int j = 0; j < 8; ++j)
        acc[n] += xf[j] * bf2f((unsigned short)wv[j]);
    }
  }

  // K-reduce across the 16 slices (lane bits 0..3)
#pragma unroll
  for (int d = 1; d < 16; d <<= 1)
#pragma unroll
    for (int n = 0; n < 32; ++n) acc[n] += __shfl_xor(acc[n], d);

  // bias + softmax over experts (all lanes redundantly, static indexing)
#pragma unroll
  for (int c = 0; c < 8; ++c) {
    float4 b = *(const float4*)(bg + c * 4);
    acc[c * 4 + 0] += b.x; acc[c * 4 + 1] += b.y;
    acc[c * 4 + 2] += b.z; acc[c * 4 + 3] += b.w;
  }
#pragma unroll
  for (int tk = 0; tk < 4; ++tk) {
    float mx = acc[tk * 8];
#pragma unroll
    for (int e = 1; e < 8; ++e) mx = fmaxf(mx, acc[tk * 8 + e]);
    float ssum = 0.f;
#pragma unroll
    for (int e = 0; e < 8; ++e) { acc[tk * 8 + e] = __expf(acc[tk * 8 + e] - mx); ssum += acc[tk * 8 + e]; }
    float inv = 1.f / ssum;
#pragma unroll
    for (int e = 0; e < 8; ++e) acc[tk * 8 + e] *= inv;
  }
  if (s == 0) {
#pragma unroll
    for (int n = 0; n < 32; ++n)
      Gt[(size_t)n * B_ROWS + m0 + r] = acc[n];
  }
}

// ---------------------------------------------------------------------------
// Kernel 2: expert GEMM + FUSED gated combine (R5-verified core). 256x256
// tile, 8 waves, BK=64, 4-phase pipelined K-loop (T3+T4), XOR-swizzle (T2),
// setprio (T5), XCD swizzle (T1). Gl staging: stride 264 + (t&31,(t>>5)*16)
// mapping -> ~2-way write banks, conflict-free reads (fixes R5's 2.49M).
// ---------------------------------------------------------------------------
__global__ __launch_bounds__(512, 2) void k_expert(const unsigned short* __restrict__ x_b,
                                                   const unsigned short* __restrict__ We_t,
                                                   const float* __restrict__ be,
                                                   const float* __restrict__ Gt,
                                                   float* __restrict__ out) {
  __shared__ unsigned short As[2][256 * 64];   // 64 KiB
  __shared__ unsigned short Bs[2][256 * 64];   // 64 KiB
  int bid = blockIdx.x;
  int t = threadIdx.x;

  // XCD swizzle: 8 consecutive same-XCD slots share one m-tile's A panel
  int xcd = bid & 7;
  int idx = bid >> 3;              // 0..63
  int m   = xcd * 8 + (idx >> 3);  // m-tile 0..63
  int hs  = idx & 7;               // h-slice 0..7 (32 cols per expert)
  int m0  = m * 256;

  int w  = t >> 6, l = t & 63;
  int wm = w >> 2, wn = w & 3;     // wave tile: rows wm*128..+128, cols wn*64..+64
  int lr = l & 15, lq = l >> 4;

  const unsigned short* Ab = x_b + (size_t)m0 * D_IN;

  const int sr = t >> 3, sg = t & 7;                 // staging row / 16B granule
  const int swz0 = ((lq ^ (lr & 7)) << 3);           // ks=0 swizzled granule (ushorts)
  const int swz1 = (((4 + lq) ^ (lr & 7)) << 3);     // ks=1
  const int arow0 = (wm * 128 + lr) << 6;            // + fm*1024
  const int brow0 = (wn * 64 + lr) << 6;             // + fn*1024

  // B global source rows for the 4 LDS rows this thread stages
  // (expert-interleaved mapping), swizzle pre-applied to source granule.
  size_t bsrc[4];
#pragma unroll
  for (int q2 = 0; q2 < 4; ++q2) {
    int rq = q2 * 64 + sr;                       // LDS row 0..255
    int me = (rq >> 3) & 7;
    int mh = hs * 32 + ((rq >> 6) & 3) * 8 + (rq & 7);
    bsrc[q2] = (size_t)(me * H_DIM + mh) * D_IN + (size_t)((sg ^ (rq & 7)) << 3);
  }

  f32x4 acc[8][4];
#pragma unroll
  for (int i = 0; i < 8; ++i)
#pragma unroll
    for (int j = 0; j < 4; ++j) acc[i][j] = (f32x4){0.f, 0.f, 0.f, 0.f};

#define STAGE_A(cb, kt, h)                                                                       \
  do {                                                                                           \
    int r0_ = (h) * 128 + sr;                                                                    \
    int r1_ = r0_ + 64;                                                                          \
    __builtin_amdgcn_global_load_lds(                                                            \
        (const __attribute__((address_space(1))) void*)(Ab + (size_t)r0_ * D_IN + (kt) * 64 +    \
                                                        ((sg ^ (r0_ & 7)) << 3)),                \
        (__attribute__((address_space(3))) void*)(&As[(cb)][r0_ * 64 + sg * 8]), 16, 0, 0);      \
    __builtin_amdgcn_global_load_lds(                                                            \
        (const __attribute__((address_space(1))) void*)(Ab + (size_t)r1_ * D_IN + (kt) * 64 +    \
                                                        ((sg ^ (r1_ & 7)) << 3)),                \
        (__attribute__((address_space(3))) void*)(&As[(cb)][r1_ * 64 + sg * 8]), 16, 0, 0);      \
  } while (0)
#define STAGE_B(cb, kt, h)                                                                       \
  do {                                                                                           \
    int r0_ = (h) * 128 + sr;                                                                    \
    int r1_ = r0_ + 64;                                                                          \
    __builtin_amdgcn_global_load_lds(                                                            \
        (const __attribute__((address_space(1))) void*)(We_t + bsrc[2 * (h)] + (kt) * 64),       \
        (__attribute__((address_space(3))) void*)(&Bs[(cb)][r0_ * 64 + sg * 8]), 16, 0, 0);      \
    __builtin_amdgcn_global_load_lds(                                                            \
        (const __attribute__((address_space(1))) void*)(We_t + bsrc[2 * (h) + 1] + (kt) * 64),   \
        (__attribute__((address_space(3))) void*)(&Bs[(cb)][r1_ * 64 + sg * 8]), 16, 0, 0);      \
  } while (0)

  // prologue: K-tile 0 fully + B of K-tile 1 (12 loads; newest 4 = B(1))
  STAGE_A(0, 0, 0); STAGE_A(0, 0, 1);
  STAGE_B(0, 0, 0); STAGE_B(0, 0, 1);
  STAGE_B(1, 1, 0); STAGE_B(1, 1, 1);
  asm volatile("s_waitcnt vmcnt(4)" ::: "memory");
  __builtin_amdgcn_s_barrier();

#pragma unroll 2
  for (int kt = 0; kt < NKT; ++kt) {
    int c = kt & 1;
    const unsigned short* Ap = &As[c][0];
    const unsigned short* Bp = &Bs[c][0];
    bf16x8 b0[4], b1[4];
#pragma unroll
    for (int q = 0; q < 4; ++q) {
      if (q == 0) {
#pragma unroll
        for (int fn = 0; fn < 4; ++fn) {
          b0[fn] = *(const bf16x8*)(Bp + brow0 + fn * 1024 + swz0);
          b1[fn] = *(const bf16x8*)(Bp + brow0 + fn * 1024 + swz1);
        }
      }
      bf16x8 a00 = *(const bf16x8*)(Ap + arow0 + (2 * q) * 1024 + swz0);
      bf16x8 a01 = *(const bf16x8*)(Ap + arow0 + (2 * q) * 1024 + swz1);
      bf16x8 a10 = *(const bf16x8*)(Ap + arow0 + (2 * q + 1) * 1024 + swz0);
      bf16x8 a11 = *(const bf16x8*)(Ap + arow0 + (2 * q + 1) * 1024 + swz1);
      if (q == 0)      { if (kt + 1 < NKT) STAGE_A(c ^ 1, kt + 1, 0); }
      else if (q == 1) { if (kt + 1 < NKT) STAGE_A(c ^ 1, kt + 1, 1); }
      else if (q == 2) { if (kt + 2 < NKT) STAGE_B(c, kt + 2, 0); }
      else             { if (kt + 2 < NKT) STAGE_B(c, kt + 2, 1); }
      __builtin_amdgcn_s_barrier();
      asm volatile("s_waitcnt lgkmcnt(0)" ::: "memory");
      __builtin_amdgcn_s_setprio(1);
#pragma unroll
      for (int fn = 0; fn < 4; ++fn) {
        acc[2 * q][fn]     = __builtin_amdgcn_mfma_f32_16x16x32_bf16(a00, b0[fn], acc[2 * q][fn], 0, 0, 0);
        acc[2 * q][fn]     = __builtin_amdgcn_mfma_f32_16x16x32_bf16(a01, b1[fn], acc[2 * q][fn], 0, 0, 0);
        acc[2 * q + 1][fn] = __builtin_amdgcn_mfma_f32_16x16x32_bf16(a10, b0[fn], acc[2 * q + 1][fn], 0, 0, 0);
        acc[2 * q + 1][fn] = __builtin_amdgcn_mfma_f32_16x16x32_bf16(a11, b1[fn], acc[2 * q + 1][fn], 0, 0, 0);
      }
      __builtin_amdgcn_s_setprio(0);
      if (q == 3) {
        if (kt < NKT - 2)        asm volatile("s_waitcnt vmcnt(4)" ::: "memory");
        else if (kt == NKT - 2)  asm volatile("s_waitcnt vmcnt(0)" ::: "memory");
      }
      __builtin_amdgcn_s_barrier();
    }
  }
#undef STAGE_A
#undef STAGE_B

  // ---- stage Gt slice (32 gate-cols x 256 rows) into LDS, reusing As ----
  // stride 264 (66 dw): write banks ~2-way; read banks conflict-free.
  float (*Gl)[264] = (float (*)[264])(&As[0][0]);   // 32x264 f32 = 33.8 KB
  {
    int n  = t & 31;             // gate-col
    int c0 = (t >> 5) * 16;      // row offset 0..240
    const float* gsrc = Gt + (size_t)n * B_ROWS + m0 + c0;
    f32x4 g0 = *(const f32x4*)(gsrc + 0);
    f32x4 g1 = *(const f32x4*)(gsrc + 4);
    f32x4 g2 = *(const f32x4*)(gsrc + 8);
    f32x4 g3 = *(const f32x4*)(gsrc + 12);
    *(f32x4*)&Gl[n][c0 + 0]  = g0;
    *(f32x4*)&Gl[n][c0 + 4]  = g1;
    *(f32x4*)&Gl[n][c0 + 8]  = g2;
    *(f32x4*)&Gl[n][c0 + 12] = g3;
  }
  __syncthreads();

  // epilogue: bias + relu + gated expert-sum + direct towers write.
  int hi = lr >> 3, h7 = lr & 7;
  int hglob = hs * 32 + wn * 8 + h7;
  float bev[4];
#pragma unroll
  for (int fn = 0; fn < 4; ++fn)
    bev[fn] = be[(2 * fn + hi) * H_DIM + hglob];
#pragma unroll
  for (int fm = 0; fm < 8; ++fm) {
    int rloc = wm * 128 + fm * 16 + lq * 4;
    int r0 = m0 + rloc;
    float vv[4][4];
#pragma unroll
    for (int fn = 0; fn < 4; ++fn)
#pragma unroll
      for (int j = 0; j < 4; ++j)
        vv[fn][j] = fmaxf(acc[fm][fn][j] + bev[fn], 0.f);
    float p[4][4];
#pragma unroll
    for (int tk = 0; tk < 4; ++tk) {
      f32x4 gv[4];
#pragma unroll
      for (int fn = 0; fn < 4; ++fn)
        gv[fn] = *(const f32x4*)&Gl[tk * 8 + 2 * fn + hi][rloc];
#pragma unroll
      for (int j = 0; j < 4; ++j)
        p[tk][j] = gv[0][j] * vv[0][j] + gv[1][j] * vv[1][j] +
                   gv[2][j] * vv[2][j] + gv[3][j] * vv[3][j];
    }
#pragma unroll
    for (int j = 0; j < 4; ++j) {
      float sa = hi ? p[0][j] : p[2][j];   // send partner-half's even task
      float sb = hi ? p[1][j] : p[3][j];   // send partner-half's odd task
      float ra = __shfl_xor(sa, 8);
      float rb = __shfl_xor(sb, 8);
      float t0 = (hi ? p[2][j] : p[0][j]) + ra;   // own even task total
      float t1 = (hi ? p[3][j] : p[1][j]) + rb;   // own odd task total
      size_t tk0 = (size_t)(hi * 2);
      out[(tk0 * B_ROWS + r0 + j) * H_DIM + hglob]       = t0;
      out[((tk0 + 1) * B_ROWS + r0 + j) * H_DIM + hglob] = t1;
    }
  }
}

extern "C" void kernel_launch(void* const* d_in, const int* in_sizes, int n_in,
                              void* d_out, int out_size, void* d_ws, size_t ws_size,
                              hipStream_t stream) {
  const float* x  = (const float*)d_in[0];
  const float* We = (const float*)d_in[1];
  const float* be = (const float*)d_in[2];
  const float* Wg = (const float*)d_in[3];
  const float* bg = (const float*)d_in[4];
  float* out = (float*)d_out;
  char* ws = (char*)d_ws;
  unsigned short* x_b  = (unsigned short*)(ws + WS_XB);
  unsigned short* We_t = (unsigned short*)(ws + WS_WET);
  float*          Gt   = (float*)(ws + WS_GT);

  k_prep_gates<<<768, 512, 0, stream>>>(x, We, Wg, x_b, We_t, bg, Gt);
  k_expert<<<512, 512, 0, stream>>>(x_b, We_t, be, Gt, out);
}